// Round 14
// baseline (35.587 us; speedup 1.0000x reference)
//
#include <hip/hip_runtime.h>
#include <hip/hip_bf16.h>

#define B_   4
#define NC_  128
#define NM_  16384
#define OUTROW 1700
#define FACTORF ((float)(27.2114 * 0.529177249))

typedef __attribute__((ext_vector_type(8))) short short8v;   // 8 x bf16 (4 VGPR)
typedef __attribute__((ext_vector_type(4))) float float4v;   // MFMA acc

__device__ __forceinline__ float fast_tanh(float x) {
    float e = __expf(2.0f * x);
    return 1.0f - 2.0f * __builtin_amdgcn_rcpf(e + 1.0f);
}
__device__ __forceinline__ unsigned short f2bf(float x) {
    union { __hip_bfloat16 h; unsigned short u; } cv;
    cv.h = __float2bfloat16(x);
    return cv.u;
}
__device__ __forceinline__ float bflo(unsigned u) { return __uint_as_float(u << 16); }
__device__ __forceinline__ float bfu(unsigned short u) { return __uint_as_float(((unsigned)u) << 16); }

union FragU { uint4 u4; unsigned u[4]; short8v s; };

// ---------------------------------------------------------------------------
// Kernel 0: fused weight-prepack (blocks 0..71) + esp/efield partials (72..).
__global__ __launch_bounds__(256) void k_prep(
    const float* __restrict__ fW1, const float* __restrict__ fW2,
    unsigned short* __restrict__ w1bf, unsigned short* __restrict__ w2bf,
    const float* __restrict__ atom_coords, const float* __restrict__ charge_coords,
    const float* __restrict__ charges, const void* __restrict__ mask,
    float4* __restrict__ partial, int nchunk)
{
    const int t = threadIdx.x;
    const int blk = blockIdx.x;
    if (blk < 36) {
        unsigned short* dst = w1bf + blk * 2048;
        const float* src = fW1 + blk * 1250;
        for (int i = t; i < 2048; i += 256) {
            int k = i >> 5, l = i & 31;
            float v = (k < 50 && l < 25) ? src[k * 25 + l] : 0.0f;
            dst[i] = f2bf(v);
        }
        return;
    }
    if (blk < 72) {
        int cp = blk - 36;
        unsigned short* dst = w2bf + cp * 7168;
        const float* src = fW2 + cp * 5000;
        for (int i = t; i < 7168; i += 256) {
            int nn = i >> 6, kk = i & 63;
            float v = (nn < 100 && kk < 50) ? src[nn * 50 + kk] : 0.0f;
            dst[i] = f2bf(v);
        }
        return;
    }
    // ---- esp part ----
    const int eb = blk - 72;
    const int b  = eb / nchunk;
    const int ch = eb % nchunk;
    const int chunkM = NM_ / nchunk;
    const int a = t & 127;
    const int h = t >> 7;

    __shared__ float4 stg[128];
    __shared__ float4 psum[128];
    __shared__ int sdet;

    if (t == 0) sdet = 0;
    __syncthreads();
    if (t < 16) {
        const uint4* mw = (const uint4*)mask;
        uint4 v = mw[b * 1024 + t];   // 256B window, in-bounds either layout
        if ((v.x > 1u) | (v.y > 1u) | (v.z > 1u) | (v.w > 1u)) atomicOr(&sdet, 1);
    }
    __syncthreads();
    const int byteMask = sdet;

    float ax, ay, az;
    {
        const float* p = atom_coords + (size_t)(b * NC_ + a) * 3;
        ax = p[0]; ay = p[1]; az = p[2];
    }
    const float* ccb = charge_coords + (size_t)b * NM_ * 3;
    const float* chb = charges + (size_t)b * NM_;
    const unsigned char* mb8 = (const unsigned char*)mask + (size_t)b * NM_;
    const int* mb32 = (const int*)mask + (size_t)b * NM_;

    float s0 = 0.0f, s1 = 0.0f, s2 = 0.0f, s3 = 0.0f;

    for (int tb = 0; tb < chunkM; tb += 128) {
        if (t < 128) {
            int m = ch * chunkM + tb + t;
            float cx = ccb[3 * m + 0], cy = ccb[3 * m + 1], cz = ccb[3 * m + 2];
            int mk = byteMask ? (int)mb8[m] : mb32[m];
            float q = mk ? chb[m] : 0.0f;
            stg[t] = make_float4(cx, cy, cz, q);
        }
        __syncthreads();
        const float4* sp = stg + h * 64;
#pragma unroll 8
        for (int i = 0; i < 64; ++i) {
            float4 cq = sp[i];
            float dx = ax - cq.x, dy = ay - cq.y, dz = az - cq.z;
            float d2 = dx * dx + dy * dy + dz * dz;
            float inv = __builtin_amdgcn_rsqf(d2);
            float inv3 = inv * inv * inv;
            s0 += cq.w * inv;
            float qi3 = cq.w * inv3;
            s1 += qi3 * dx; s2 += qi3 * dy; s3 += qi3 * dz;
        }
        __syncthreads();
    }
    if (h == 1) psum[a] = make_float4(s0, s1, s2, s3);
    __syncthreads();
    if (h == 0) {
        float4 o = psum[a];
        partial[(size_t)(b * NC_ + a) * nchunk + ch] =
            make_float4(s0 + o.x, s1 + o.y, s2 + o.z, s3 + o.w);
    }
}

// ---------------------------------------------------------------------------
// Kernel 1: r13 structure, ABLATION: L2 phase executes twice (idempotent)
// so dur delta = one L2-phase time; doubled kernel may surface in rocprof.
__global__ __launch_bounds__(512, 6) void k_ef(
    const float* __restrict__ atom_coords, const float4* __restrict__ partial, int nchunk,
    const int* __restrict__ atom_types,
    const float* __restrict__ eW0, const float* __restrict__ eb0,
    const float* __restrict__ eW1, const float* __restrict__ eb1,
    const float* __restrict__ eW2, const float* __restrict__ eb2,
    const float* __restrict__ fW0, const float* __restrict__ fb0,
    const float* __restrict__ fb1, const float* __restrict__ fb2,
    const unsigned short* __restrict__ w1bf, const unsigned short* __restrict__ w2bf,
    float* __restrict__ out)
{
    const int t   = threadIdx.x;
    const int blk = blockIdx.x;
    const int b   = blk >> 7;
    const int n   = blk & 127;

    __shared__ float cst[NC_][3];
    __shared__ float xs[128];
    __shared__ int   sc[128];
    __shared__ int   tat[128];
    __shared__ int   wcnt[2][6];
    __shared__ int   tmeta[16];     // base | (c<<8) | (pend<<12)
    __shared__ int   tcnt;
    __shared__ unsigned short a0s[6][25];
    __shared__ unsigned short b0s[6][25];
    __shared__ float b1s[6][50];
    __shared__ unsigned short b2s[6][100];
    __shared__ float espf[4];
    __shared__ float h0e[25];
    __shared__ float h1e[52];
    __shared__ __align__(16) unsigned short y1p[128][72];    // 18432 B
    __shared__ __align__(16) unsigned short y2t[100][136];   // 27200 B
    unsigned short (*y0p)[32] = (unsigned short (*)[32])&y2t[0][0];

    const int tn = atom_types[n];
    const int c0 = tn * 6;
    const int wv   = t >> 6;
    const int lane = t & 63;

    // ---- stage + partial reduce ----
    for (int idx = t; idx < NC_ * 3; idx += 512)
        (&cst[0][0])[idx] = atom_coords[(size_t)b * NC_ * 3 + idx];
    if (t < 128) tat[t] = atom_types[t];
    for (int idx = t; idx < 150; idx += 512) {
        (&a0s[0][0])[idx] = f2bf(fW0[c0 * 25 + idx]);
        (&b0s[0][0])[idx] = f2bf(fb0[c0 * 25 + idx]);
    }
    if (t >= 192 && t < 492) (&b1s[0][0])[t - 192] = fb1[c0 * 50 + t - 192];
    if (t >= 128 && t < 192) {
        for (int idx = t - 128; idx < 600; idx += 64)
            (&b2s[0][0])[idx] = f2bf(fb2[c0 * 100 + idx]);
    }
    if (t >= 256 && t < 320) {
        int lt = t - 256;
        float4 v = make_float4(0.f, 0.f, 0.f, 0.f);
        for (int ch = lt; ch < nchunk; ch += 64) {
            float4 u = partial[(size_t)(b * NC_ + n) * nchunk + ch];
            v.x += u.x; v.y += u.y; v.z += u.z; v.w += u.w;
        }
#pragma unroll
        for (int off = 32; off > 0; off >>= 1) {
            v.x += __shfl_xor(v.x, off, 64);
            v.y += __shfl_xor(v.y, off, 64);
            v.z += __shfl_xor(v.z, off, 64);
            v.w += __shfl_xor(v.w, off, 64);
        }
        if (lt == 0) {
            espf[0] = v.x * FACTORF;
            espf[1] = v.y * FACTORF;
            espf[2] = v.z * FACTORF;
            espf[3] = v.w * FACTORF;
        }
    }
    __syncthreads();

    // ---- phase A: proj + channel + ballots (waves 0-1) || esp L0 ----
    unsigned long long mkeep = 0;
    int myc = 0; float px = 0.0f;
    if (wv < 2) {
        const bool valid = t < 127;
        if (valid) {
            int jn = (t < n) ? t : t + 1;
            float rx = cst[n][0] - cst[jn][0];
            float ry = cst[n][1] - cst[jn][1];
            float rz = cst[n][2] - cst[jn][2];
            float d2 = rx * rx + ry * ry + rz * rz;
            px = (rx * espf[1] + ry * espf[2] + rz * espf[3]) / d2;
            myc = tat[jn];
        }
#pragma unroll
        for (int v = 0; v < 6; ++v) {
            unsigned long long m = __ballot(valid && (myc == v));
            if (valid && myc == v) mkeep = m;
            if (lane == 0) wcnt[wv][v] = __builtin_popcountll(m);
        }
    } else if (t >= 320 && t < 345) {
        int l = t - 320;
        h0e[l] = fast_tanh(eW0[tn * 25 + l] * espf[0] + eb0[tn * 25 + l]);
    }
    __syncthreads();

    // ---- phase B: O(1) scatter + tile meta || esp L1 ----
    if (t < 127) {
        int w0[6], w1[6];
#pragma unroll
        for (int v = 0; v < 6; ++v) { w0[v] = wcnt[0][v]; w1[v] = wcnt[1][v]; }
        int basec = 0;
#pragma unroll
        for (int v = 0; v < 6; ++v) if (v < myc) basec += w0[v] + w1[v];
        int pos = basec + (wv == 1 ? w0[myc] : 0)
                + __builtin_popcountll(mkeep & ((1ull << lane) - 1ull));
        sc[pos] = myc; xs[pos] = px;
        if (t == 0) {
            int run = 0, nt = 0;
#pragma unroll
            for (int v = 0; v < 6; ++v) {
                int pendv = run + w0[v] + w1[v];
                for (int base = run; base < pendv; base += 16) {
                    tmeta[nt] = base | (v << 8) | (pendv << 12);
                    ++nt;
                }
                run = pendv;
            }
            tcnt = nt;
        }
    } else if (t >= 320 && t < 370) {
        int l = t - 320;
        float s = eb1[tn * 50 + l];
        const float* wr = eW1 + (size_t)(tn * 50 + l) * 25;
#pragma unroll
        for (int j = 0; j < 25; ++j) s += wr[j] * h0e[j];
        h1e[l] = fast_tanh(s) + h0e[l % 25];
    }
    __syncthreads();

    // ---- phase C: Y0 (waves 0-3) || esp L2 -> out ----
    if (t < 256) {
        for (int i = t; i < 127 * 32; i += 256) {
            int r = i >> 5, l = i & 31;
            int c = sc[r]; float x = xs[r];
            float v = (l < 25) ? fast_tanh(bfu(a0s[c][l]) * x + bfu(b0s[c][l])) : 0.0f;
            y0p[r][l] = f2bf(v);
        }
    } else if (t >= 320 && t < 420) {
        int k = t - 320;
        float s = eb2[tn * 100 + k];
        const float2* wr = (const float2*)(eW2 + (size_t)(tn * 100 + k) * 50);
#pragma unroll
        for (int j = 0; j < 25; ++j) {
            float2 u = wr[j];
            s += u.x * h1e[2 * j] + u.y * h1e[2 * j + 1];
        }
        out[(size_t)(b * NC_ + n) * OUTROW + k] = fast_tanh(s) + h1e[k % 50];
    }
    __syncthreads();

    // ---- L1 (MFMA): Y1 = tanh(W1·Y0 + b1) + Id·Y0.
    //      Wave wv: neuron-tile wv&3, row-tiles (wv>>2)::2. ----
    {
        const int kt = wv & 3;
        const int krow = (lane >> 4) << 3;
        const int arow = kt * 16 + (lane & 15);
        const int kres = (arow < 50) ? (arow % 25) : 999;
        FragU Id;
#pragma unroll
        for (int e = 0; e < 4; ++e) {
            int ka = krow + 2 * e;
            Id.u[e] = (ka == kres ? 0x3f80u : 0u) | (ka + 1 == kres ? 0x3f800000u : 0u);
        }
        const unsigned short* wb = w1bf + ((size_t)c0 * 64 + arow) * 32 + krow;
        int meta = (lane < 16) ? tmeta[lane & 15] : 0;
        const int nt = tcnt;
        const int kb = kt * 16 + ((lane >> 4) << 2);
        int ccur = -1;
        FragU Af;
        float bias[4];
        for (int ti = (wv >> 2); ti < nt; ti += 2) {
            const int mv = __builtin_amdgcn_readlane(meta, ti);
            const int base = mv & 255, c = (mv >> 8) & 15, pend = mv >> 12;
            if (c != ccur) {
                ccur = c;
                Af.u4 = *(const uint4*)(wb + (size_t)c * 2048);
#pragma unroll
                for (int r = 0; r < 4; ++r)
                    bias[r] = (kb + r < 50) ? b1s[c][kb + r] : 0.0f;
            }
            FragU Bf;
            Bf.u4 = *(const uint4*)&y0p[base + (lane & 15)][krow];
            float4v z = {0.f, 0.f, 0.f, 0.f};
            float4v acc  = __builtin_amdgcn_mfma_f32_16x16x32_bf16(Af.s, Bf.s, z, 0, 0, 0);
            float4v acc2 = __builtin_amdgcn_mfma_f32_16x16x32_bf16(Id.s, Bf.s, z, 0, 0, 0);
            const int p = base + (lane & 15);
            if (p < pend) {
                unsigned short yv[4];
#pragma unroll
                for (int r = 0; r < 4; ++r)
                    yv[r] = f2bf(fast_tanh(acc[r] + bias[r]) + acc2[r]);
                unsigned lo = (unsigned)yv[0] | ((unsigned)yv[1] << 16);
                unsigned hi = (unsigned)yv[2] | ((unsigned)yv[3] << 16);
                *(uint2*)&y1p[p][kb] = make_uint2(lo, hi);
            }
        }
    }
    __syncthreads();   // y0p (y2t alias) dead from here

    // ======== ABLATION: L2 phase executed TWICE (idempotent rewrites) =======
    for (int rep2 = 0; rep2 < 2; ++rep2) {

    // ---- L2 (MFMA): Y2T[nn][p] = tanh(W2[nn]·Y1[p] + b2) + Id·Y1.
    //      Wave wv (<7) owns nn-tile wv; wave 7 zeroes y2t col 127. ----
    if (wv < 7) {
        const int krow = (lane >> 4) << 3;
        const int arow = wv * 16 + (lane & 15);
        const int nres = (arow < 100) ? (arow % 50) : 999;
        FragU Id0, Id1;
#pragma unroll
        for (int e = 0; e < 4; ++e) {
            int ka = krow + 2 * e;
            Id0.u[e] = (ka == nres ? 0x3f80u : 0u) | (ka + 1 == nres ? 0x3f800000u : 0u);
            int kc = 32 + krow + 2 * e;
            Id1.u[e] = (kc == nres ? 0x3f80u : 0u) | (kc + 1 == nres ? 0x3f800000u : 0u);
        }
        int meta = (lane < 16) ? tmeta[lane & 15] : 0;
        const int nt = tcnt;
        const int nb = wv * 16 + ((lane >> 4) << 2);
        int ccur = -1;
        FragU A0, A1;
        float bb[4];
        for (int ti = 0; ti < nt; ++ti) {
            const int mv = __builtin_amdgcn_readlane(meta, ti);
            const int base = mv & 255, c = (mv >> 8) & 15, pend = mv >> 12;
            if (c != ccur) {
                ccur = c;
                const unsigned short* wb =
                    w2bf + ((size_t)(c0 + c) * 112 + arow) * 64;
                A0.u4 = *(const uint4*)(wb + krow);
                A1.u4 = *(const uint4*)(wb + 32 + krow);
#pragma unroll
                for (int r = 0; r < 4; ++r)
                    bb[r] = (nb + r < 100) ? bfu(b2s[c][nb + r]) : 0.0f;
            }
            FragU B0, B1;
            const int p = base + (lane & 15);
            B0.u4 = *(const uint4*)&y1p[p][krow];
            B1.u4 = *(const uint4*)&y1p[p][32 + krow];
            float4v z = {0.f, 0.f, 0.f, 0.f};
            float4v acc  = __builtin_amdgcn_mfma_f32_16x16x32_bf16(A0.s, B0.s, z, 0, 0, 0);
            acc  = __builtin_amdgcn_mfma_f32_16x16x32_bf16(A1.s, B1.s, acc, 0, 0, 0);
            float4v acc2 = __builtin_amdgcn_mfma_f32_16x16x32_bf16(Id0.s, B0.s, z, 0, 0, 0);
            acc2 = __builtin_amdgcn_mfma_f32_16x16x32_bf16(Id1.s, B1.s, acc2, 0, 0, 0);
            if (p < pend) {
#pragma unroll
                for (int r = 0; r < 4; ++r) {
                    int nn = nb + r;
                    if (nn < 100)
                        y2t[nn][p] = f2bf(fast_tanh(acc[r] + bb[r]) + acc2[r]);
                }
            }
        }
    } else {
        for (int i = lane; i < 100; i += 64) y2t[i][127] = 0;
    }
    __syncthreads();

    }   // end rep2

    // ---- Gram (MFMA): G[m][a] = sum_p Y2T[m][p]*Y2T[a][p]; K=128 (col 127=0).
    if (wv < 7) {
        const int krow = (lane >> 4) << 3;
        short8v GB[4];
#pragma unroll
        for (int ks = 0; ks < 4; ++ks) {
            FragU cv; cv.u4 = *(const uint4*)&y2t[lane & 15][ks * 32 + krow];
            GB[ks] = cv.s;
        }
        float* orow = out + (size_t)(b * NC_ + n) * OUTROW + 100;
        const int aa = lane & 15;
        int m0 = wv * 16 + (lane & 15);
        if (m0 > 99) m0 = 99;      // clamp: rows >=100 don't exist; outputs discarded
        float4v acc = {0.f, 0.f, 0.f, 0.f};
#pragma unroll
        for (int ks = 0; ks < 4; ++ks) {
            FragU av; av.u4 = *(const uint4*)&y2t[m0][ks * 32 + krow];
            acc = __builtin_amdgcn_mfma_f32_16x16x32_bf16(av.s, GB[ks], acc, 0, 0, 0);
        }
        const int mrow = wv * 16 + ((lane >> 4) << 2);
#pragma unroll
        for (int r = 0; r < 4; ++r) {
            int m = mrow + r;
            if (m < 100) orow[m * 16 + aa] = 2.0f * acc[r];
        }
    }
}

// ---------------------------------------------------------------------------
extern "C" void kernel_launch(void* const* d_in, const int* in_sizes, int n_in,
                              void* d_out, int out_size, void* d_ws, size_t ws_size,
                              hipStream_t stream) {
    (void)in_sizes; (void)n_in; (void)out_size;
    const float* atom_coords   = (const float*)d_in[0];
    const float* charge_coords = (const float*)d_in[1];
    const float* charges       = (const float*)d_in[2];
    const float* eW0 = (const float*)d_in[3];
    const float* eb0 = (const float*)d_in[4];
    const float* eW1 = (const float*)d_in[5];
    const float* eb1 = (const float*)d_in[6];
    const float* eW2 = (const float*)d_in[7];
    const float* eb2 = (const float*)d_in[8];
    const float* fW0 = (const float*)d_in[9];
    const float* fb0 = (const float*)d_in[10];
    const float* fW1 = (const float*)d_in[11];
    const float* fb1 = (const float*)d_in[12];
    const float* fW2 = (const float*)d_in[13];
    const float* fb2 = (const float*)d_in[14];
    const int*   atom_types = (const int*)d_in[15];
    const void*  mask = d_in[16];
    float* out = (float*)d_out;

    // ws layout: [w1bf 147456B][w2bf 516096B][partial B*NC*nchunk*16]
    const size_t W1BF_B = 36 * 64 * 32 * 2;     // 147456
    const size_t W2BF_B = 36 * 112 * 64 * 2;    // 516096
    unsigned short* w1bf = (unsigned short*)d_ws;
    unsigned short* w2bf = (unsigned short*)((char*)d_ws + W1BF_B);
    float4* partial = (float4*)((char*)d_ws + W1BF_B + W2BF_B);

    int nchunk = 128;
    while (nchunk > 1 &&
           W1BF_B + W2BF_B + (size_t)B_ * NC_ * nchunk * 16 > ws_size)
        nchunk >>= 1;

    k_prep<<<72 + B_ * nchunk, 256, 0, stream>>>(
        fW1, fW2, w1bf, w2bf,
        atom_coords, charge_coords, charges, mask, partial, nchunk);
    k_ef<<<B_ * NC_, 512, 0, stream>>>(
        atom_coords, partial, nchunk, atom_types,
        eW0, eb0, eW1, eb1, eW2, eb2,
        fW0, fb0, fb1, fb2, w1bf, w2bf, out);
}

// Round 15
// 28.962 us; speedup vs baseline: 1.2287x; 1.2287x over previous
//
#include <hip/hip_runtime.h>
#include <hip/hip_bf16.h>

#define B_   4
#define NC_  128
#define NM_  16384
#define OUTROW 1700
#define FACTORF ((float)(27.2114 * 0.529177249))

typedef __attribute__((ext_vector_type(8))) short short8v;   // 8 x bf16 (4 VGPR)
typedef __attribute__((ext_vector_type(4))) float float4v;   // MFMA acc

__device__ __forceinline__ float fast_tanh(float x) {
    float e = __expf(2.0f * x);
    return 1.0f - 2.0f * __builtin_amdgcn_rcpf(e + 1.0f);
}
__device__ __forceinline__ unsigned short f2bf(float x) {
    union { __hip_bfloat16 h; unsigned short u; } cv;
    cv.h = __float2bfloat16(x);
    return cv.u;
}
__device__ __forceinline__ float bflo(unsigned u) { return __uint_as_float(u << 16); }
__device__ __forceinline__ float bfu(unsigned short u) { return __uint_as_float(((unsigned)u) << 16); }

union FragU { uint4 u4; unsigned u[4]; short8v s; };

// ---------------------------------------------------------------------------
// Kernel 0: fused weight-prepack (blocks 0..71) + esp/efield partials (72..).
__global__ __launch_bounds__(256) void k_prep(
    const float* __restrict__ fW1, const float* __restrict__ fW2,
    unsigned short* __restrict__ w1bf, unsigned short* __restrict__ w2bf,
    const float* __restrict__ atom_coords, const float* __restrict__ charge_coords,
    const float* __restrict__ charges, const void* __restrict__ mask,
    float4* __restrict__ partial, int nchunk)
{
    const int t = threadIdx.x;
    const int blk = blockIdx.x;
    if (blk < 36) {
        unsigned short* dst = w1bf + blk * 2048;
        const float* src = fW1 + blk * 1250;
        for (int i = t; i < 2048; i += 256) {
            int k = i >> 5, l = i & 31;
            float v = (k < 50 && l < 25) ? src[k * 25 + l] : 0.0f;
            dst[i] = f2bf(v);
        }
        return;
    }
    if (blk < 72) {
        int cp = blk - 36;
        unsigned short* dst = w2bf + cp * 7168;
        const float* src = fW2 + cp * 5000;
        for (int i = t; i < 7168; i += 256) {
            int nn = i >> 6, kk = i & 63;
            float v = (nn < 100 && kk < 50) ? src[nn * 50 + kk] : 0.0f;
            dst[i] = f2bf(v);
        }
        return;
    }
    // ---- esp part ----
    const int eb = blk - 72;
    const int b  = eb / nchunk;
    const int ch = eb % nchunk;
    const int chunkM = NM_ / nchunk;
    const int a = t & 127;
    const int h = t >> 7;

    __shared__ float4 stg[128];
    __shared__ float4 psum[128];
    __shared__ int sdet;

    if (t == 0) sdet = 0;
    __syncthreads();
    if (t < 16) {
        const uint4* mw = (const uint4*)mask;
        uint4 v = mw[b * 1024 + t];   // 256B window, in-bounds either layout
        if ((v.x > 1u) | (v.y > 1u) | (v.z > 1u) | (v.w > 1u)) atomicOr(&sdet, 1);
    }
    __syncthreads();
    const int byteMask = sdet;

    float ax, ay, az;
    {
        const float* p = atom_coords + (size_t)(b * NC_ + a) * 3;
        ax = p[0]; ay = p[1]; az = p[2];
    }
    const float* ccb = charge_coords + (size_t)b * NM_ * 3;
    const float* chb = charges + (size_t)b * NM_;
    const unsigned char* mb8 = (const unsigned char*)mask + (size_t)b * NM_;
    const int* mb32 = (const int*)mask + (size_t)b * NM_;

    float s0 = 0.0f, s1 = 0.0f, s2 = 0.0f, s3 = 0.0f;

    for (int tb = 0; tb < chunkM; tb += 128) {
        if (t < 128) {
            int m = ch * chunkM + tb + t;
            float cx = ccb[3 * m + 0], cy = ccb[3 * m + 1], cz = ccb[3 * m + 2];
            int mk = byteMask ? (int)mb8[m] : mb32[m];
            float q = mk ? chb[m] : 0.0f;
            stg[t] = make_float4(cx, cy, cz, q);
        }
        __syncthreads();
        const float4* sp = stg + h * 64;
#pragma unroll 8
        for (int i = 0; i < 64; ++i) {
            float4 cq = sp[i];
            float dx = ax - cq.x, dy = ay - cq.y, dz = az - cq.z;
            float d2 = dx * dx + dy * dy + dz * dz;
            float inv = __builtin_amdgcn_rsqf(d2);
            float inv3 = inv * inv * inv;
            s0 += cq.w * inv;
            float qi3 = cq.w * inv3;
            s1 += qi3 * dx; s2 += qi3 * dy; s3 += qi3 * dz;
        }
        __syncthreads();
    }
    if (h == 1) psum[a] = make_float4(s0, s1, s2, s3);
    __syncthreads();
    if (h == 0) {
        float4 o = psum[a];
        partial[(size_t)(b * NC_ + a) * nchunk + ch] =
            make_float4(s0 + o.x, s1 + o.y, s2 + o.z, s3 + o.w);
    }
}

// ---------------------------------------------------------------------------
// Kernel 1: reduce partials + esp MLP + ef MLP (MFMA) + Gram (MFMA).
// r13 base + L2 operand-swap (vectorized y2t stores) + vectorized Y0 writes.
__global__ __launch_bounds__(512, 6) void k_ef(
    const float* __restrict__ atom_coords, const float4* __restrict__ partial, int nchunk,
    const int* __restrict__ atom_types,
    const float* __restrict__ eW0, const float* __restrict__ eb0,
    const float* __restrict__ eW1, const float* __restrict__ eb1,
    const float* __restrict__ eW2, const float* __restrict__ eb2,
    const float* __restrict__ fW0, const float* __restrict__ fb0,
    const float* __restrict__ fb1, const float* __restrict__ fb2,
    const unsigned short* __restrict__ w1bf, const unsigned short* __restrict__ w2bf,
    float* __restrict__ out)
{
    const int t   = threadIdx.x;
    const int blk = blockIdx.x;
    const int b   = blk >> 7;
    const int n   = blk & 127;

    __shared__ float cst[NC_][3];
    __shared__ float xs[128];
    __shared__ int   sc[128];
    __shared__ int   tat[128];
    __shared__ int   wcnt[2][6];
    __shared__ int   tmeta[16];     // base | (c<<8) | (pend<<12)
    __shared__ int   tcnt;
    __shared__ unsigned short a0s[6][25];
    __shared__ unsigned short b0s[6][25];
    __shared__ float b1s[6][50];
    __shared__ unsigned short b2s[6][100];
    __shared__ float espf[4];
    __shared__ float h0e[25];
    __shared__ float h1e[52];
    __shared__ __align__(16) unsigned short y1p[128][72];    // 18432 B
    __shared__ __align__(16) unsigned short y2t[100][136];   // 27200 B
    unsigned short (*y0p)[32] = (unsigned short (*)[32])&y2t[0][0];

    const int tn = atom_types[n];
    const int c0 = tn * 6;
    const int wv   = t >> 6;
    const int lane = t & 63;

    // ---- stage + partial reduce ----
    for (int idx = t; idx < NC_ * 3; idx += 512)
        (&cst[0][0])[idx] = atom_coords[(size_t)b * NC_ * 3 + idx];
    if (t < 128) tat[t] = atom_types[t];
    for (int idx = t; idx < 150; idx += 512) {
        (&a0s[0][0])[idx] = f2bf(fW0[c0 * 25 + idx]);
        (&b0s[0][0])[idx] = f2bf(fb0[c0 * 25 + idx]);
    }
    if (t >= 192 && t < 492) (&b1s[0][0])[t - 192] = fb1[c0 * 50 + t - 192];
    if (t >= 128 && t < 192) {
        for (int idx = t - 128; idx < 600; idx += 64)
            (&b2s[0][0])[idx] = f2bf(fb2[c0 * 100 + idx]);
    }
    if (t >= 256 && t < 320) {
        int lt = t - 256;
        float4 v = make_float4(0.f, 0.f, 0.f, 0.f);
        for (int ch = lt; ch < nchunk; ch += 64) {
            float4 u = partial[(size_t)(b * NC_ + n) * nchunk + ch];
            v.x += u.x; v.y += u.y; v.z += u.z; v.w += u.w;
        }
#pragma unroll
        for (int off = 32; off > 0; off >>= 1) {
            v.x += __shfl_xor(v.x, off, 64);
            v.y += __shfl_xor(v.y, off, 64);
            v.z += __shfl_xor(v.z, off, 64);
            v.w += __shfl_xor(v.w, off, 64);
        }
        if (lt == 0) {
            espf[0] = v.x * FACTORF;
            espf[1] = v.y * FACTORF;
            espf[2] = v.z * FACTORF;
            espf[3] = v.w * FACTORF;
        }
    }
    __syncthreads();

    // ---- phase A: proj + channel + ballots (waves 0-1) || esp L0 ----
    unsigned long long mkeep = 0;
    int myc = 0; float px = 0.0f;
    if (wv < 2) {
        const bool valid = t < 127;
        if (valid) {
            int jn = (t < n) ? t : t + 1;
            float rx = cst[n][0] - cst[jn][0];
            float ry = cst[n][1] - cst[jn][1];
            float rz = cst[n][2] - cst[jn][2];
            float d2 = rx * rx + ry * ry + rz * rz;
            px = (rx * espf[1] + ry * espf[2] + rz * espf[3]) / d2;
            myc = tat[jn];
        }
#pragma unroll
        for (int v = 0; v < 6; ++v) {
            unsigned long long m = __ballot(valid && (myc == v));
            if (valid && myc == v) mkeep = m;
            if (lane == 0) wcnt[wv][v] = __builtin_popcountll(m);
        }
    } else if (t >= 320 && t < 345) {
        int l = t - 320;
        h0e[l] = fast_tanh(eW0[tn * 25 + l] * espf[0] + eb0[tn * 25 + l]);
    }
    __syncthreads();

    // ---- phase B: O(1) scatter + tile meta || esp L1 ----
    if (t < 127) {
        int w0[6], w1[6];
#pragma unroll
        for (int v = 0; v < 6; ++v) { w0[v] = wcnt[0][v]; w1[v] = wcnt[1][v]; }
        int basec = 0;
#pragma unroll
        for (int v = 0; v < 6; ++v) if (v < myc) basec += w0[v] + w1[v];
        int pos = basec + (wv == 1 ? w0[myc] : 0)
                + __builtin_popcountll(mkeep & ((1ull << lane) - 1ull));
        sc[pos] = myc; xs[pos] = px;
        if (t == 0) {
            int run = 0, nt = 0;
#pragma unroll
            for (int v = 0; v < 6; ++v) {
                int pendv = run + w0[v] + w1[v];
                for (int base = run; base < pendv; base += 16) {
                    tmeta[nt] = base | (v << 8) | (pendv << 12);
                    ++nt;
                }
                run = pendv;
            }
            tcnt = nt;
        }
    } else if (t >= 320 && t < 370) {
        int l = t - 320;
        float s = eb1[tn * 50 + l];
        const float* wr = eW1 + (size_t)(tn * 50 + l) * 25;
#pragma unroll
        for (int j = 0; j < 25; ++j) s += wr[j] * h0e[j];
        h1e[l] = fast_tanh(s) + h0e[l % 25];
    }
    __syncthreads();

    // ---- phase C: Y0 vectorized (waves 0-3) || esp L2 -> out ----
    if (t < 256) {
        for (int i = t; i < 127 * 8; i += 256) {
            int r = i >> 3, q = i & 7;
            int c = sc[r]; float x = xs[r];
            unsigned short v4[4];
#pragma unroll
            for (int e = 0; e < 4; ++e) {
                int l = 4 * q + e;
                v4[e] = (l < 25)
                      ? f2bf(fast_tanh(bfu(a0s[c][l]) * x + bfu(b0s[c][l])))
                      : (unsigned short)0;
            }
            unsigned lo = (unsigned)v4[0] | ((unsigned)v4[1] << 16);
            unsigned hi = (unsigned)v4[2] | ((unsigned)v4[3] << 16);
            *(uint2*)&y0p[r][4 * q] = make_uint2(lo, hi);
        }
    } else if (t >= 320 && t < 420) {
        int k = t - 320;
        float s = eb2[tn * 100 + k];
        const float2* wr = (const float2*)(eW2 + (size_t)(tn * 100 + k) * 50);
#pragma unroll
        for (int j = 0; j < 25; ++j) {
            float2 u = wr[j];
            s += u.x * h1e[2 * j] + u.y * h1e[2 * j + 1];
        }
        out[(size_t)(b * NC_ + n) * OUTROW + k] = fast_tanh(s) + h1e[k % 50];
    }
    __syncthreads();

    // ---- L1 (MFMA): Y1 = tanh(W1·Y0 + b1) + Id·Y0.
    //      Wave wv: neuron-tile wv&3, row-tiles (wv>>2)::2. ----
    {
        const int kt = wv & 3;
        const int krow = (lane >> 4) << 3;
        const int arow = kt * 16 + (lane & 15);
        const int kres = (arow < 50) ? (arow % 25) : 999;
        FragU Id;
#pragma unroll
        for (int e = 0; e < 4; ++e) {
            int ka = krow + 2 * e;
            Id.u[e] = (ka == kres ? 0x3f80u : 0u) | (ka + 1 == kres ? 0x3f800000u : 0u);
        }
        const unsigned short* wb = w1bf + ((size_t)c0 * 64 + arow) * 32 + krow;
        int meta = (lane < 16) ? tmeta[lane & 15] : 0;
        const int nt = tcnt;
        const int kb = kt * 16 + ((lane >> 4) << 2);
        int ccur = -1;
        FragU Af;
        float bias[4];
        for (int ti = (wv >> 2); ti < nt; ti += 2) {
            const int mv = __builtin_amdgcn_readlane(meta, ti);
            const int base = mv & 255, c = (mv >> 8) & 15, pend = mv >> 12;
            if (c != ccur) {
                ccur = c;
                Af.u4 = *(const uint4*)(wb + (size_t)c * 2048);
#pragma unroll
                for (int r = 0; r < 4; ++r)
                    bias[r] = (kb + r < 50) ? b1s[c][kb + r] : 0.0f;
            }
            FragU Bf;
            Bf.u4 = *(const uint4*)&y0p[base + (lane & 15)][krow];
            float4v z = {0.f, 0.f, 0.f, 0.f};
            float4v acc  = __builtin_amdgcn_mfma_f32_16x16x32_bf16(Af.s, Bf.s, z, 0, 0, 0);
            float4v acc2 = __builtin_amdgcn_mfma_f32_16x16x32_bf16(Id.s, Bf.s, z, 0, 0, 0);
            const int p = base + (lane & 15);
            if (p < pend) {
                unsigned short yv[4];
#pragma unroll
                for (int r = 0; r < 4; ++r)
                    yv[r] = f2bf(fast_tanh(acc[r] + bias[r]) + acc2[r]);
                unsigned lo = (unsigned)yv[0] | ((unsigned)yv[1] << 16);
                unsigned hi = (unsigned)yv[2] | ((unsigned)yv[3] << 16);
                *(uint2*)&y1p[p][kb] = make_uint2(lo, hi);
            }
        }
    }
    __syncthreads();   // y0p (y2t alias) dead from here

    // ---- L2 (MFMA, operand-swapped): D = Y1·W2^T -> lane holds fixed nn,
    //      4 consecutive p => vectorized y2t stores. Wave wv (<7): nn-tile wv.
    //      Wave 7 zeroes y2t col 127 (K-pad for Gram). ----
    if (wv < 7) {
        const int krow = (lane >> 4) << 3;
        const int arow = wv * 16 + (lane & 15);       // nn of this lane
        const bool nok = arow < 100;
        const int nres = nok ? (arow % 50) : 999;
        FragU Id0, Id1;
#pragma unroll
        for (int e = 0; e < 4; ++e) {
            int ka = krow + 2 * e;
            Id0.u[e] = (ka == nres ? 0x3f80u : 0u) | (ka + 1 == nres ? 0x3f800000u : 0u);
            int kc = 32 + krow + 2 * e;
            Id1.u[e] = (kc == nres ? 0x3f80u : 0u) | (kc + 1 == nres ? 0x3f800000u : 0u);
        }
        int meta = (lane < 16) ? tmeta[lane & 15] : 0;
        const int nt = tcnt;
        const int prow_off = (lane >> 4) << 2;
        int ccur = -1;
        FragU A0, A1;
        float bb = 0.0f;
        for (int ti = 0; ti < nt; ++ti) {
            const int mv = __builtin_amdgcn_readlane(meta, ti);
            const int base = mv & 255, c = (mv >> 8) & 15, pend = mv >> 12;
            if (c != ccur) {
                ccur = c;
                const unsigned short* wb =
                    w2bf + ((size_t)(c0 + c) * 112 + arow) * 64;
                A0.u4 = *(const uint4*)(wb + krow);
                A1.u4 = *(const uint4*)(wb + 32 + krow);
                bb = nok ? bfu(b2s[c][arow]) : 0.0f;
            }
            FragU B0, B1;
            B0.u4 = *(const uint4*)&y1p[base + (lane & 15)][krow];
            B1.u4 = *(const uint4*)&y1p[base + (lane & 15)][32 + krow];
            float4v z = {0.f, 0.f, 0.f, 0.f};
            // swapped: first arg = Y1 rows (-> D rows = p), second = W2 rows (-> D cols = nn)
            float4v acc  = __builtin_amdgcn_mfma_f32_16x16x32_bf16(B0.s, A0.s, z, 0, 0, 0);
            acc  = __builtin_amdgcn_mfma_f32_16x16x32_bf16(B1.s, A1.s, acc, 0, 0, 0);
            float4v acc2 = __builtin_amdgcn_mfma_f32_16x16x32_bf16(B0.s, Id0.s, z, 0, 0, 0);
            acc2 = __builtin_amdgcn_mfma_f32_16x16x32_bf16(B1.s, Id1.s, acc2, 0, 0, 0);
            if (nok) {
                const int prow = base + prow_off;
                unsigned short yv[4];
#pragma unroll
                for (int r = 0; r < 4; ++r)
                    yv[r] = f2bf(fast_tanh(acc[r] + bb) + acc2[r]);
                if (prow + 3 < pend) {
                    unsigned lo = (unsigned)yv[0] | ((unsigned)yv[1] << 16);
                    unsigned hi = (unsigned)yv[2] | ((unsigned)yv[3] << 16);
                    *(uint2*)&y2t[arow][prow] = make_uint2(lo, hi);
                } else {
#pragma unroll
                    for (int r = 0; r < 4; ++r)
                        if (prow + r < pend) y2t[arow][prow + r] = yv[r];
                }
            }
        }
    } else {
        for (int i = lane; i < 100; i += 64) y2t[i][127] = 0;
    }
    __syncthreads();

    // ---- Gram (MFMA): G[m][a] = sum_p Y2T[m][p]*Y2T[a][p]; K=128 (col 127=0).
    if (wv < 7) {
        const int krow = (lane >> 4) << 3;
        short8v GB[4];
#pragma unroll
        for (int ks = 0; ks < 4; ++ks) {
            FragU cv; cv.u4 = *(const uint4*)&y2t[lane & 15][ks * 32 + krow];
            GB[ks] = cv.s;
        }
        float* orow = out + (size_t)(b * NC_ + n) * OUTROW + 100;
        const int aa = lane & 15;
        int m0 = wv * 16 + (lane & 15);
        if (m0 > 99) m0 = 99;      // clamp: rows >=100 don't exist; outputs discarded
        float4v acc = {0.f, 0.f, 0.f, 0.f};
#pragma unroll
        for (int ks = 0; ks < 4; ++ks) {
            FragU av; av.u4 = *(const uint4*)&y2t[m0][ks * 32 + krow];
            acc = __builtin_amdgcn_mfma_f32_16x16x32_bf16(av.s, GB[ks], acc, 0, 0, 0);
        }
        const int mrow = wv * 16 + ((lane >> 4) << 2);
#pragma unroll
        for (int r = 0; r < 4; ++r) {
            int m = mrow + r;
            if (m < 100) orow[m * 16 + aa] = 2.0f * acc[r];
        }
    }
}

// ---------------------------------------------------------------------------
extern "C" void kernel_launch(void* const* d_in, const int* in_sizes, int n_in,
                              void* d_out, int out_size, void* d_ws, size_t ws_size,
                              hipStream_t stream) {
    (void)in_sizes; (void)n_in; (void)out_size;
    const float* atom_coords   = (const float*)d_in[0];
    const float* charge_coords = (const float*)d_in[1];
    const float* charges       = (const float*)d_in[2];
    const float* eW0 = (const float*)d_in[3];
    const float* eb0 = (const float*)d_in[4];
    const float* eW1 = (const float*)d_in[5];
    const float* eb1 = (const float*)d_in[6];
    const float* eW2 = (const float*)d_in[7];
    const float* eb2 = (const float*)d_in[8];
    const float* fW0 = (const float*)d_in[9];
    const float* fb0 = (const float*)d_in[10];
    const float* fW1 = (const float*)d_in[11];
    const float* fb1 = (const float*)d_in[12];
    const float* fW2 = (const float*)d_in[13];
    const float* fb2 = (const float*)d_in[14];
    const int*   atom_types = (const int*)d_in[15];
    const void*  mask = d_in[16];
    float* out = (float*)d_out;

    // ws layout: [w1bf 147456B][w2bf 516096B][partial B*NC*nchunk*16]
    const size_t W1BF_B = 36 * 64 * 32 * 2;     // 147456
    const size_t W2BF_B = 36 * 112 * 64 * 2;    // 516096
    unsigned short* w1bf = (unsigned short*)d_ws;
    unsigned short* w2bf = (unsigned short*)((char*)d_ws + W1BF_B);
    float4* partial = (float4*)((char*)d_ws + W1BF_B + W2BF_B);

    int nchunk = 128;
    while (nchunk > 1 &&
           W1BF_B + W2BF_B + (size_t)B_ * NC_ * nchunk * 16 > ws_size)
        nchunk >>= 1;

    k_prep<<<72 + B_ * nchunk, 256, 0, stream>>>(
        fW1, fW2, w1bf, w2bf,
        atom_coords, charge_coords, charges, mask, partial, nchunk);
    k_ef<<<B_ * NC_, 512, 0, stream>>>(
        atom_coords, partial, nchunk, atom_types,
        eW0, eb0, eW1, eb1, eW2, eb2,
        fW0, fb0, fb1, fb2, w1bf, w2bf, out);
}